// Round 12
// baseline (233.640 us; speedup 1.0000x reference)
//
#include <hip/hip_runtime.h>
#include <hip/hip_bf16.h>
#include <cstdint>
#include <cstddef>

typedef __attribute__((ext_vector_type(8))) short short8;
typedef __attribute__((ext_vector_type(4))) float floatx4;
typedef __attribute__((ext_vector_type(16))) float floatx16;
typedef unsigned short u16;

__device__ __forceinline__ u16 f2bf(float f) {
  unsigned u = __float_as_uint(f);
  u += 0x7FFFu + ((u >> 16) & 1u);
  return (u16)(u >> 16);
}

__device__ __forceinline__ unsigned cvt_pk_bf16(float a, float b) {
  unsigned r;
  asm("v_cvt_pk_bf16_f32 %0, %1, %2" : "=v"(r) : "v"(a), "v"(b));
  return r;
}

// raw 2^x. TRANS op: use the builtin so the compiler handles the
// TRANS->VALU-consumer wait-state hazard (inline asm hid it -> R8 corruption).
__device__ __forceinline__ float fexp2(float x) {
#if __has_builtin(__builtin_amdgcn_exp2f)
  return __builtin_amdgcn_exp2f(x);
#else
  float r;
  asm("v_exp_f32 %0, %1\n\ts_nop 1" : "=v"(r) : "v"(x));
  return r;
#endif
}

__device__ __forceinline__ float frcp(float x) {
#if __has_builtin(__builtin_amdgcn_rcpf)
  return __builtin_amdgcn_rcpf(x);
#else
  float r;
  asm("v_rcp_f32 %0, %1\n\ts_nop 1" : "=v"(r) : "v"(x));
  return r;
#endif
}

// async global -> LDS, 16B per lane. LDS dest = wave-uniform base + lane*16.
__device__ __forceinline__ void gload16(const u16* g, u16* l) {
  __builtin_amdgcn_global_load_lds(
      (const __attribute__((address_space(1))) void*)g,
      (__attribute__((address_space(3))) void*)l, 16, 0, 0);
}

// ---------------- f32 -> bf16 convert: 3 buffers in one launch ----------------
__global__ void cvt3_kernel(const float* __restrict__ a, u16* __restrict__ oa, int na4,
                            const float* __restrict__ b, u16* __restrict__ ob, int nb4,
                            const float* __restrict__ c, u16* __restrict__ oc, int nc4) {
  int i = blockIdx.x * blockDim.x + threadIdx.x;
  int stride = gridDim.x * blockDim.x;
  int ntot = na4 + nb4 + nc4;
  for (int idx = i; idx < ntot; idx += stride) {
    const float* src; u16* dst; int j = idx;
    if (j < na4)            { src = a; dst = oa; }
    else if (j < na4 + nb4) { src = b; dst = ob; j -= na4; }
    else                    { src = c; dst = oc; j -= na4 + nb4; }
    float4 v = reinterpret_cast<const float4*>(src)[j];
    ushort4 o = make_ushort4(f2bf(v.x), f2bf(v.y), f2bf(v.z), f2bf(v.w));
    reinterpret_cast<ushort4*>(dst)[j] = o;
  }
}

// ---------------- C = A @ B^T + bias, 256x256 tile, 8 waves, dbuf LDS ----------
// Wave (wm = w>>2, wn = w&3) owns a 128x64 output: acc[8][4] 16x16 frags ->
// 32 MFMA per 12 ds_read_b128 per K-step (2.67 FLOP/read vs 2.0 at 128^2) so
// the per-CU MFMA floor (~1030 cyc/step) exceeds LDS time (~450) -> MFMA-bound.
// Same proven 2-phase loop: issue next step's 4 global_load_lds, ds_read+MFMA,
// one s_barrier with vmcnt(0). XCD-chunked block mapping (grid % 8 == 0).
// Columns < qcols additionally scaled by qscale (folds softmax scale into Q).
template<bool OUTF32>
__global__ __launch_bounds__(512, 2) void gemm_bt256(
    const u16* __restrict__ A, const u16* __restrict__ B,
    const float* __restrict__ bias, void* __restrict__ Cout,
    int M, int N, int K, int qcols, float qscale)
{
  __shared__ u16 As[2 * 256 * 32];   // 32 KB
  __shared__ u16 Bs[2 * 256 * 32];   // 32 KB
  const int tid = threadIdx.x;
  const int lane = tid & 63, w = tid >> 6;          // 8 waves
  const int l15 = lane & 15, lhi = lane >> 4;
  const int wm = w >> 2, wn = w & 3;

  const int mblocks = M >> 8;        // %8 == 0 (M = 16384 -> 64)
  const int nb = N >> 8;
  const int bid = blockIdx.x;
  const int xcd = bid & 7;
  const int local = bid >> 3;
  const int mpx = mblocks >> 3;      // m-tiles per XCD
  const int m0 = (xcd * mpx + local / nb) << 8;
  const int n0 = (local % nb) << 8;

  const int srow = tid >> 2;                        // 0..127
  const int scol = (tid & 3) * 8;
  const u16* aptr = A + (size_t)(m0 + srow) * K + scol;
  const u16* bptr = B + (size_t)(n0 + srow) * K + scol;
  const size_t r128 = (size_t)128 * K;

  const int ksteps = K >> 5;
  const int wbase = w * 512;                        // elements; wave covers 1KB

  floatx4 acc[8][4] = {};

  // prologue: stage K-step 0 into buffer 0, drain, publish
  gload16(aptr,        As + wbase);
  gload16(aptr + r128, As + 4096 + wbase);
  gload16(bptr,        Bs + wbase);
  gload16(bptr + r128, Bs + 4096 + wbase);
  asm volatile("s_waitcnt vmcnt(0)" ::: "memory");
  __builtin_amdgcn_s_barrier();
  __builtin_amdgcn_sched_barrier(0);

  const int rowA = wm * 128 + l15;
  const int rowB = wn * 64 + l15;
  const int kof = lhi * 8;

  int cur = 0;
  for (int t = 0; t < ksteps; ++t) {
    const int nxt = cur ^ 1;
    if (t + 1 < ksteps) {            // issue next step's loads first (hide latency)
      const int k1 = (t + 1) << 5;
      gload16(aptr + k1,        As + nxt * 8192 + wbase);
      gload16(aptr + k1 + r128, As + nxt * 8192 + 4096 + wbase);
      gload16(bptr + k1,        Bs + nxt * 8192 + wbase);
      gload16(bptr + k1 + r128, Bs + nxt * 8192 + 4096 + wbase);
    }

    const u16* Ab = As + cur * 8192;
    const u16* Bb = Bs + cur * 8192;
    short8 af[8], bf[4];
#pragma unroll
    for (int i = 0; i < 8; ++i)
      af[i] = *reinterpret_cast<const short8*>(&Ab[(rowA + i * 16) * 32 + kof]);
#pragma unroll
    for (int j = 0; j < 4; ++j)
      bf[j] = *reinterpret_cast<const short8*>(&Bb[(rowB + j * 16) * 32 + kof]);

    __builtin_amdgcn_s_setprio(1);
#pragma unroll
    for (int i = 0; i < 8; ++i)
#pragma unroll
      for (int j = 0; j < 4; ++j)
        acc[i][j] = __builtin_amdgcn_mfma_f32_16x16x32_bf16(af[i], bf[j], acc[i][j], 0, 0, 0);
    __builtin_amdgcn_s_setprio(0);

    if (t + 1 < ksteps) {            // next step's tiles ready; cur fully read
      asm volatile("s_waitcnt vmcnt(0)" ::: "memory");
      __builtin_amdgcn_s_barrier();
      __builtin_amdgcn_sched_barrier(0);
    }
    cur = nxt;
  }

#pragma unroll
  for (int i = 0; i < 8; ++i)
#pragma unroll
    for (int j = 0; j < 4; ++j) {
      int row = m0 + wm * 128 + i * 16 + lhi * 4;
      int col = n0 + wn * 64 + j * 16 + l15;
      float bv = bias[col];
      float sc = (col < qcols) ? qscale : 1.0f;
#pragma unroll
      for (int r = 0; r < 4; ++r) {
        float v = (acc[i][j][r] + bv) * sc;
        if (OUTF32) reinterpret_cast<float*>(Cout)[(size_t)(row + r) * N + col] = v;
        else        reinterpret_cast<u16*>(Cout)[(size_t)(row + r) * N + col] = f2bf(v);
      }
    }
}

// ---------------- V transpose: qkv V-part -> vt[(b*12+h)*64 + d][s] ----------------
__global__ __launch_bounds__(256) void vtrans_kernel(
    const u16* __restrict__ qkv, u16* __restrict__ vt)
{
  __shared__ u16 T[64][72];
  const int idx = blockIdx.x;
  const int st = idx & 15;
  const int bh = idx >> 4;
  const int b = bh / 12, h = bh % 12;
  const int t = threadIdx.x;
  const int r2 = t >> 3, c8 = (t & 7) * 8;

  const u16* src = qkv + ((size_t)(b * 1024 + st * 64)) * 2304 + 1536 + h * 64;
#pragma unroll
  for (int rr = 0; rr < 2; ++rr) {
    int s = rr * 32 + r2;
    short8 v = *reinterpret_cast<const short8*>(src + (size_t)s * 2304 + c8);
    *reinterpret_cast<short8*>(&T[s][c8]) = v;
  }
  __syncthreads();
  u16* dst = vt + (size_t)bh * 64 * 1024 + st * 64;
#pragma unroll
  for (int rr = 0; rr < 2; ++rr) {
    int d = rr * 32 + r2;
    short8 o;
#pragma unroll
    for (int j = 0; j < 8; ++j) o[j] = T[c8 + j][d];
    *reinterpret_cast<short8*>(dst + (size_t)d * 1024 + c8) = o;
  }
}

// ---------------- fused flash attention v8: 8-wave blocks (256 q-rows), raw
// exp2 (hazard-safe builtin), static softmax + MFMA row-sums, pointer-increment
// staging, permlane32_swap pack (s_nop-guarded) ----------
__global__ __launch_bounds__(512) void attn8_kernel(
    const u16* __restrict__ qkv, const u16* __restrict__ vt, u16* __restrict__ z)
{
  constexpr int LDK = 72;
  __shared__ u16 Ks[64 * LDK];   // [key][d]
  __shared__ u16 Vs[64 * LDK];   // [d][key]

  const int tid = threadIdx.x;
  const int lane = tid & 63, w = tid >> 6;    // w = 0..7
  const int l31 = lane & 31, hi = lane >> 5;

  const int idx = blockIdx.x;
  const int head = idx % 192;        // all 4 q-blocks of a head share idx%8 -> same XCD
  const int qt   = idx / 192;        // 0..3
  const int b = head / 12, h = head % 12;

  const size_t rowbase = (size_t)b * 1024;
  const u16* Qp  = qkv + rowbase * 2304 + h * 64;
  const u16* Kp  = Qp + 768;
  const u16* Vtp = vt + (size_t)head * 64 * 1024;

  const int q0 = qt * 256 + w * 32;

  short8 qf[4];
#pragma unroll
  for (int c = 0; c < 4; ++c)
    qf[c] = *reinterpret_cast<const short8*>(
        Qp + (size_t)(q0 + l31) * 2304 + c * 16 + hi * 8);

  // ones B-fragment for MFMA row-sum (bf16 1.0 = 0x3F80)
  union { unsigned u[4]; short8 v; } ONE;
#pragma unroll
  for (int i = 0; i < 4; ++i) ONE.u[i] = 0x3F803F80u;
  const short8 ones = ONE.v;

  const int srow = tid >> 3, scol = (tid & 7) * 8;   // 512 lanes cover 64 rows x 64 cols

  // staging pointers: advance by constant stride per tile (no per-tile muls)
  const u16* kstage = Kp + (size_t)srow * 2304 + scol;
  const u16* vstage = Vtp + (size_t)srow * 1024 + scol;
  constexpr size_t KADV = (size_t)64 * 2304;   // next 64 keys (rows of K)
  constexpr size_t VADV = 64;                  // next 64 keys (cols of vt)

  // hoisted LDS addresses
  u16* const ksw = &Ks[srow * LDK + scol];
  u16* const vsw = &Vs[srow * LDK + scol];
  const u16* const ks0 = &Ks[l31 * LDK + hi * 8];
  const u16* const ks1 = ks0 + 32 * LDK;
  const u16* const vs0 = &Vs[l31 * LDK + hi * 8];
  const u16* const vs1 = vs0 + 32 * LDK;

  // prologue: stage tile 0 into regs (one K + one V short8 per lane)
  short8 kvr = *reinterpret_cast<const short8*>(kstage);
  short8 vvr = *reinterpret_cast<const short8*>(vstage);
  kstage += KADV; vstage += VADV;

  floatx16 oacc0 = {}, oacc1 = {}, lacc = {};

  for (int kt = 0; kt < 16; ++kt) {
    __syncthreads();               // all waves done reading previous tile
    *reinterpret_cast<short8*>(ksw) = kvr;
    *reinterpret_cast<short8*>(vsw) = vvr;
    __syncthreads();               // tile resident

    if (kt < 15) {                 // issue next tile's loads; complete under compute
      kvr = *reinterpret_cast<const short8*>(kstage);
      vvr = *reinterpret_cast<const short8*>(vstage);
      kstage += KADV; vstage += VADV;
    }

    // S(key, q)
    floatx16 s0 = {}, s1 = {};
    __builtin_amdgcn_s_setprio(1);
#pragma unroll
    for (int c = 0; c < 4; ++c) {
      short8 kf0 = *reinterpret_cast<const short8*>(ks0 + c * 16);
      short8 kf1 = *reinterpret_cast<const short8*>(ks1 + c * 16);
      s0 = __builtin_amdgcn_mfma_f32_32x32x16_bf16(kf0, qf[c], s0, 0, 0, 0);
      s1 = __builtin_amdgcn_mfma_f32_32x32x16_bf16(kf1, qf[c], s1, 0, 0, 0);
    }
    __builtin_amdgcn_s_setprio(0);

    // p = 2^s (static softmax; s already in log2 units)
#pragma unroll
    for (int r = 0; r < 16; ++r) {
      s0[r] = fexp2(s0[r]);
      s1[r] = fexp2(s1[r]);
    }

    // P -> bf16 A-frags: cvt_pk + v_permlane32_swap (s_nop guards the
    // VALU-write -> permlane-read hazard; sources written by cvt_pk just above)
    short8 pa[4];
#pragma unroll
    for (int c = 0; c < 4; ++c) {
      const floatx16& sv = (c >> 1) ? s1 : s0;
      const int B0 = (c & 1) * 8, B1 = B0 + 4;
      unsigned x0 = cvt_pk_bf16(sv[B0],     sv[B0 + 1]);
      unsigned x1 = cvt_pk_bf16(sv[B0 + 2], sv[B0 + 3]);
      unsigned y0 = cvt_pk_bf16(sv[B1],     sv[B1 + 1]);
      unsigned y1 = cvt_pk_bf16(sv[B1 + 2], sv[B1 + 3]);
      asm("s_nop 1\n\tv_permlane32_swap_b32 %0, %1" : "+v"(x0), "+v"(y0));
      asm("s_nop 1\n\tv_permlane32_swap_b32 %0, %1" : "+v"(x1), "+v"(y1));
      union { unsigned u[4]; short8 v; } P;
      P.u[0] = x0; P.u[1] = x1; P.u[2] = y0; P.u[3] = y1;
      pa[c] = P.v;
    }

    // O += P @ V ; l += P @ 1  (all on the MFMA pipe)
    __builtin_amdgcn_s_setprio(1);
#pragma unroll
    for (int c = 0; c < 4; ++c) {
      short8 vf0 = *reinterpret_cast<const short8*>(vs0 + c * 16);
      short8 vf1 = *reinterpret_cast<const short8*>(vs1 + c * 16);
      oacc0 = __builtin_amdgcn_mfma_f32_32x32x16_bf16(pa[c], vf0, oacc0, 0, 0, 0);
      oacc1 = __builtin_amdgcn_mfma_f32_32x32x16_bf16(pa[c], vf1, oacc1, 0, 0, 0);
      lacc  = __builtin_amdgcn_mfma_f32_32x32x16_bf16(pa[c], ones, lacc, 0, 0, 0);
    }
    __builtin_amdgcn_s_setprio(0);
  }

  // epilogue: out = oacc / lacc  (identical lane layout, no cross-lane ops)
#pragma unroll
  for (int r = 0; r < 16; ++r) {
    int q = (r & 3) + 8 * (r >> 2) + 4 * hi;
    float li = frcp(lacc[r]);
    size_t orow = (rowbase + q0 + q) * (size_t)768 + h * 64;
    z[orow + l31]      = f2bf(oacc0[r] * li);
    z[orow + 32 + l31] = f2bf(oacc1[r] * li);
  }
}

extern "C" void kernel_launch(void* const* d_in, const int* in_sizes, int n_in,
                              void* d_out, int out_size, void* d_ws, size_t ws_size,
                              hipStream_t stream) {
  (void)in_sizes; (void)n_in; (void)out_size; (void)ws_size;
  const float* x      = (const float*)d_in[0];
  const float* w_qkv  = (const float*)d_in[1];
  const float* b_qkv  = (const float*)d_in[2];
  const float* w_proj = (const float*)d_in[3];
  const float* b_proj = (const float*)d_in[4];
  float* out = (float*)d_out;

  const int BS = 16 * 1024;  // B*S rows
  const int D = 768, N3 = 2304;
  const float QSC = 0.180336880f;    // 0.125 * log2(e)

  u16* xb  = (u16*)d_ws;                     // [BS, D]   (reused as vt after gemm1)
  u16* wqb = xb  + (size_t)BS * D;           // [N3, D]
  u16* wpb = wqb + (size_t)N3 * D;           // [D, D]
  u16* qkv = wpb + (size_t)D * D;            // [BS, N3]
  u16* zb  = qkv + (size_t)BS * N3;          // [BS, D]
  u16* vtb = xb;                             // aliases xb

  cvt3_kernel<<<2048, 256, 0, stream>>>(x, xb, BS * D / 4,
                                        w_qkv, wqb, N3 * D / 4,
                                        w_proj, wpb, D * D / 4);

  gemm_bt256<false><<<(BS / 256) * (N3 / 256), 512, 0, stream>>>(
      xb, wqb, b_qkv, qkv, BS, N3, D, 768, QSC);
  vtrans_kernel<<<192 * 16, 256, 0, stream>>>(qkv, vtb);
  attn8_kernel<<<192 * 4, 512, 0, stream>>>(qkv, vtb, zb);
  gemm_bt256<true><<<(BS / 256) * (D / 256), 512, 0, stream>>>(
      zb, wpb, b_proj, out, BS, D, D, 0, 1.0f);
}

// Round 13
// 214.219 us; speedup vs baseline: 1.0907x; 1.0907x over previous
//
#include <hip/hip_runtime.h>
#include <hip/hip_bf16.h>
#include <cstdint>
#include <cstddef>

typedef __attribute__((ext_vector_type(8))) short short8;
typedef __attribute__((ext_vector_type(4))) float floatx4;
typedef __attribute__((ext_vector_type(16))) float floatx16;
typedef unsigned short u16;

__device__ __forceinline__ u16 f2bf(float f) {
  unsigned u = __float_as_uint(f);
  u += 0x7FFFu + ((u >> 16) & 1u);
  return (u16)(u >> 16);
}

__device__ __forceinline__ unsigned cvt_pk_bf16(float a, float b) {
  unsigned r;
  asm("v_cvt_pk_bf16_f32 %0, %1, %2" : "=v"(r) : "v"(a), "v"(b));
  return r;
}

// raw 2^x. TRANS op: use the builtin so the compiler handles the
// TRANS->VALU-consumer wait-state hazard (inline asm hid it -> R8 corruption).
__device__ __forceinline__ float fexp2(float x) {
#if __has_builtin(__builtin_amdgcn_exp2f)
  return __builtin_amdgcn_exp2f(x);
#else
  float r;
  asm("v_exp_f32 %0, %1\n\ts_nop 1" : "=v"(r) : "v"(x));
  return r;
#endif
}

__device__ __forceinline__ float frcp(float x) {
#if __has_builtin(__builtin_amdgcn_rcpf)
  return __builtin_amdgcn_rcpf(x);
#else
  float r;
  asm("v_rcp_f32 %0, %1\n\ts_nop 1" : "=v"(r) : "v"(x));
  return r;
#endif
}

// async global -> LDS, 16B per lane. LDS dest = wave-uniform base + lane*16.
__device__ __forceinline__ void gload16(const u16* g, u16* l) {
  __builtin_amdgcn_global_load_lds(
      (const __attribute__((address_space(1))) void*)g,
      (__attribute__((address_space(3))) void*)l, 16, 0, 0);
}

// ---------------- f32 -> bf16 convert: 3 buffers in one launch ----------------
__global__ void cvt3_kernel(const float* __restrict__ a, u16* __restrict__ oa, int na4,
                            const float* __restrict__ b, u16* __restrict__ ob, int nb4,
                            const float* __restrict__ c, u16* __restrict__ oc, int nc4) {
  int i = blockIdx.x * blockDim.x + threadIdx.x;
  int stride = gridDim.x * blockDim.x;
  int ntot = na4 + nb4 + nc4;
  for (int idx = i; idx < ntot; idx += stride) {
    const float* src; u16* dst; int j = idx;
    if (j < na4)            { src = a; dst = oa; }
    else if (j < na4 + nb4) { src = b; dst = ob; j -= na4; }
    else                    { src = c; dst = oc; j -= na4 + nb4; }
    float4 v = reinterpret_cast<const float4*>(src)[j];
    ushort4 o = make_ushort4(f2bf(v.x), f2bf(v.y), f2bf(v.z), f2bf(v.w));
    reinterpret_cast<ushort4*>(dst)[j] = o;
  }
}

// ---------------- C = A @ B^T + bias, 128x128 tile, 3-slot ring, counted vmcnt ----
// T4: loads for tile t+2 issued at iter t and stay in flight ACROSS the barrier
// (vmcnt(4), never 0 mid-loop). Tile t+1's loads are a full iteration old at the
// wait -> barrier is pure sync, not a drain. Ring-3 hazard: buf[(t+2)%3] was
// last read in iter t-1, whose reads retired before that iter's end barrier.
// XCD-local mapping: xcd = bid&7 owns a contiguous m-chunk, n innermost.
// Columns < qcols additionally scaled by qscale (folds softmax scale into Q).
template<bool OUTF32>
__global__ __launch_bounds__(256) void gemm_bt128(
    const u16* __restrict__ A, const u16* __restrict__ B,
    const float* __restrict__ bias, void* __restrict__ Cout,
    int M, int N, int K, int qcols, float qscale)
{
  __shared__ u16 As[3 * 128 * 32];   // 24 KB
  __shared__ u16 Bs[3 * 128 * 32];   // 24 KB
  const int tid = threadIdx.x;
  const int lane = tid & 63, w = tid >> 6;
  const int l15 = lane & 15, lhi = lane >> 4;
  const int wm = w >> 1, wn = w & 1;

  const int mblocks = M >> 7;        // %8 == 0
  const int nb = N >> 7;
  const int bid = blockIdx.x;
  const int xcd = bid & 7;
  const int local = bid >> 3;
  const int mpx = mblocks >> 3;      // m-tiles per XCD
  const int m0 = (xcd * mpx + local / nb) << 7;
  const int n0 = (local % nb) << 7;

  const int srow = tid >> 2;
  const int scol = (tid & 3) * 8;
  const u16* aptr = A + (size_t)(m0 + srow) * K + scol;
  const u16* bptr = B + (size_t)(n0 + srow) * K + scol;
  const size_t r64 = (size_t)64 * K;

  const int ksteps = K >> 5;
  const int wbase = w * 512;

  floatx4 acc[4][4] = {};

  // prologue: stage tiles 0 and 1, wait for tile 0 only
  {
    gload16(aptr,       As + wbase);
    gload16(aptr + r64, As + 2048 + wbase);
    gload16(bptr,       Bs + wbase);
    gload16(bptr + r64, Bs + 2048 + wbase);
    gload16(aptr + 32,       As + 4096 + wbase);
    gload16(aptr + 32 + r64, As + 4096 + 2048 + wbase);
    gload16(bptr + 32,       Bs + 4096 + wbase);
    gload16(bptr + 32 + r64, Bs + 4096 + 2048 + wbase);
  }
  asm volatile("s_waitcnt vmcnt(4)" ::: "memory");
  __builtin_amdgcn_s_barrier();
  __builtin_amdgcn_sched_barrier(0);

  int bc = 0, bs = 2;                // compute buf of tile t; stage buf of t+2
  for (int t = 0; t < ksteps; ++t) {
    if (t + 2 < ksteps) {            // issue tile t+2 (in flight across barrier)
      const int k2 = (t + 2) << 5;
      const int sb = bs * 4096;
      gload16(aptr + k2,       As + sb + wbase);
      gload16(aptr + k2 + r64, As + sb + 2048 + wbase);
      gload16(bptr + k2,       Bs + sb + wbase);
      gload16(bptr + k2 + r64, Bs + sb + 2048 + wbase);
    }

    const u16* Ab = As + bc * 4096;
    const u16* Bb = Bs + bc * 4096;
    short8 af[4], bf[4];
#pragma unroll
    for (int i = 0; i < 4; ++i) {
      af[i] = *reinterpret_cast<const short8*>(&Ab[(wm * 64 + i * 16 + l15) * 32 + lhi * 8]);
      bf[i] = *reinterpret_cast<const short8*>(&Bb[(wn * 64 + i * 16 + l15) * 32 + lhi * 8]);
    }
    __builtin_amdgcn_s_setprio(1);
#pragma unroll
    for (int i = 0; i < 4; ++i)
#pragma unroll
      for (int j = 0; j < 4; ++j)
        acc[i][j] = __builtin_amdgcn_mfma_f32_16x16x32_bf16(af[i], bf[j], acc[i][j], 0, 0, 0);
    __builtin_amdgcn_s_setprio(0);

    if (t + 1 < ksteps) {            // ensure tile t+1 resident; keep t+2 in flight
      if (t + 2 < ksteps) asm volatile("s_waitcnt vmcnt(4)" ::: "memory");
      else                asm volatile("s_waitcnt vmcnt(0)" ::: "memory");
      __builtin_amdgcn_s_barrier();
      __builtin_amdgcn_sched_barrier(0);
    }
    bc = (bc == 2) ? 0 : bc + 1;
    bs = (bs == 2) ? 0 : bs + 1;
  }

#pragma unroll
  for (int i = 0; i < 4; ++i)
#pragma unroll
    for (int j = 0; j < 4; ++j) {
      int row = m0 + wm * 64 + i * 16 + lhi * 4;
      int col = n0 + wn * 64 + j * 16 + l15;
      float bv = bias[col];
      float sc = (col < qcols) ? qscale : 1.0f;
#pragma unroll
      for (int r = 0; r < 4; ++r) {
        float v = (acc[i][j][r] + bv) * sc;
        if (OUTF32) reinterpret_cast<float*>(Cout)[(size_t)(row + r) * N + col] = v;
        else        reinterpret_cast<u16*>(Cout)[(size_t)(row + r) * N + col] = f2bf(v);
      }
    }
}

// ---------------- V transpose: qkv V-part -> vt[(b*12+h)*64 + d][s] ----------------
__global__ __launch_bounds__(256) void vtrans_kernel(
    const u16* __restrict__ qkv, u16* __restrict__ vt)
{
  __shared__ u16 T[64][72];
  const int idx = blockIdx.x;
  const int st = idx & 15;
  const int bh = idx >> 4;
  const int b = bh / 12, h = bh % 12;
  const int t = threadIdx.x;
  const int r2 = t >> 3, c8 = (t & 7) * 8;

  const u16* src = qkv + ((size_t)(b * 1024 + st * 64)) * 2304 + 1536 + h * 64;
#pragma unroll
  for (int rr = 0; rr < 2; ++rr) {
    int s = rr * 32 + r2;
    short8 v = *reinterpret_cast<const short8*>(src + (size_t)s * 2304 + c8);
    *reinterpret_cast<short8*>(&T[s][c8]) = v;
  }
  __syncthreads();
  u16* dst = vt + (size_t)bh * 64 * 1024 + st * 64;
#pragma unroll
  for (int rr = 0; rr < 2; ++rr) {
    int d = rr * 32 + r2;
    short8 o;
#pragma unroll
    for (int j = 0; j < 8; ++j) o[j] = T[c8 + j][d];
    *reinterpret_cast<short8*>(dst + (size_t)d * 1024 + c8) = o;
  }
}

// ---------------- fused flash attention v8: 8-wave blocks (256 q-rows), raw
// exp2 (hazard-safe builtin), static softmax + MFMA row-sums, pointer-increment
// staging, permlane32_swap pack (s_nop-guarded) ----------
__global__ __launch_bounds__(512) void attn8_kernel(
    const u16* __restrict__ qkv, const u16* __restrict__ vt, u16* __restrict__ z)
{
  constexpr int LDK = 72;
  __shared__ u16 Ks[64 * LDK];   // [key][d]
  __shared__ u16 Vs[64 * LDK];   // [d][key]

  const int tid = threadIdx.x;
  const int lane = tid & 63, w = tid >> 6;    // w = 0..7
  const int l31 = lane & 31, hi = lane >> 5;

  const int idx = blockIdx.x;
  const int head = idx % 192;        // all 4 q-blocks of a head share idx%8 -> same XCD
  const int qt   = idx / 192;        // 0..3
  const int b = head / 12, h = head % 12;

  const size_t rowbase = (size_t)b * 1024;
  const u16* Qp  = qkv + rowbase * 2304 + h * 64;
  const u16* Kp  = Qp + 768;
  const u16* Vtp = vt + (size_t)head * 64 * 1024;

  const int q0 = qt * 256 + w * 32;

  short8 qf[4];
#pragma unroll
  for (int c = 0; c < 4; ++c)
    qf[c] = *reinterpret_cast<const short8*>(
        Qp + (size_t)(q0 + l31) * 2304 + c * 16 + hi * 8);

  // ones B-fragment for MFMA row-sum (bf16 1.0 = 0x3F80)
  union { unsigned u[4]; short8 v; } ONE;
#pragma unroll
  for (int i = 0; i < 4; ++i) ONE.u[i] = 0x3F803F80u;
  const short8 ones = ONE.v;

  const int srow = tid >> 3, scol = (tid & 7) * 8;   // 512 lanes cover 64 rows x 64 cols

  // staging pointers: advance by constant stride per tile (no per-tile muls)
  const u16* kstage = Kp + (size_t)srow * 2304 + scol;
  const u16* vstage = Vtp + (size_t)srow * 1024 + scol;
  constexpr size_t KADV = (size_t)64 * 2304;   // next 64 keys (rows of K)
  constexpr size_t VADV = 64;                  // next 64 keys (cols of vt)

  // hoisted LDS addresses
  u16* const ksw = &Ks[srow * LDK + scol];
  u16* const vsw = &Vs[srow * LDK + scol];
  const u16* const ks0 = &Ks[l31 * LDK + hi * 8];
  const u16* const ks1 = ks0 + 32 * LDK;
  const u16* const vs0 = &Vs[l31 * LDK + hi * 8];
  const u16* const vs1 = vs0 + 32 * LDK;

  // prologue: stage tile 0 into regs (one K + one V short8 per lane)
  short8 kvr = *reinterpret_cast<const short8*>(kstage);
  short8 vvr = *reinterpret_cast<const short8*>(vstage);
  kstage += KADV; vstage += VADV;

  floatx16 oacc0 = {}, oacc1 = {}, lacc = {};

  for (int kt = 0; kt < 16; ++kt) {
    __syncthreads();               // all waves done reading previous tile
    *reinterpret_cast<short8*>(ksw) = kvr;
    *reinterpret_cast<short8*>(vsw) = vvr;
    __syncthreads();               // tile resident

    if (kt < 15) {                 // issue next tile's loads; complete under compute
      kvr = *reinterpret_cast<const short8*>(kstage);
      vvr = *reinterpret_cast<const short8*>(vstage);
      kstage += KADV; vstage += VADV;
    }

    // S(key, q)
    floatx16 s0 = {}, s1 = {};
    __builtin_amdgcn_s_setprio(1);
#pragma unroll
    for (int c = 0; c < 4; ++c) {
      short8 kf0 = *reinterpret_cast<const short8*>(ks0 + c * 16);
      short8 kf1 = *reinterpret_cast<const short8*>(ks1 + c * 16);
      s0 = __builtin_amdgcn_mfma_f32_32x32x16_bf16(kf0, qf[c], s0, 0, 0, 0);
      s1 = __builtin_amdgcn_mfma_f32_32x32x16_bf16(kf1, qf[c], s1, 0, 0, 0);
    }
    __builtin_amdgcn_s_setprio(0);

    // p = 2^s (static softmax; s already in log2 units)
#pragma unroll
    for (int r = 0; r < 16; ++r) {
      s0[r] = fexp2(s0[r]);
      s1[r] = fexp2(s1[r]);
    }

    // P -> bf16 A-frags: cvt_pk + v_permlane32_swap (s_nop guards the
    // VALU-write -> permlane-read hazard; sources written by cvt_pk just above)
    short8 pa[4];
#pragma unroll
    for (int c = 0; c < 4; ++c) {
      const floatx16& sv = (c >> 1) ? s1 : s0;
      const int B0 = (c & 1) * 8, B1 = B0 + 4;
      unsigned x0 = cvt_pk_bf16(sv[B0],     sv[B0 + 1]);
      unsigned x1 = cvt_pk_bf16(sv[B0 + 2], sv[B0 + 3]);
      unsigned y0 = cvt_pk_bf16(sv[B1],     sv[B1 + 1]);
      unsigned y1 = cvt_pk_bf16(sv[B1 + 2], sv[B1 + 3]);
      asm("s_nop 1\n\tv_permlane32_swap_b32 %0, %1" : "+v"(x0), "+v"(y0));
      asm("s_nop 1\n\tv_permlane32_swap_b32 %0, %1" : "+v"(x1), "+v"(y1));
      union { unsigned u[4]; short8 v; } P;
      P.u[0] = x0; P.u[1] = x1; P.u[2] = y0; P.u[3] = y1;
      pa[c] = P.v;
    }

    // O += P @ V ; l += P @ 1  (all on the MFMA pipe)
    __builtin_amdgcn_s_setprio(1);
#pragma unroll
    for (int c = 0; c < 4; ++c) {
      short8 vf0 = *reinterpret_cast<const short8*>(vs0 + c * 16);
      short8 vf1 = *reinterpret_cast<const short8*>(vs1 + c * 16);
      oacc0 = __builtin_amdgcn_mfma_f32_32x32x16_bf16(pa[c], vf0, oacc0, 0, 0, 0);
      oacc1 = __builtin_amdgcn_mfma_f32_32x32x16_bf16(pa[c], vf1, oacc1, 0, 0, 0);
      lacc  = __builtin_amdgcn_mfma_f32_32x32x16_bf16(pa[c], ones, lacc, 0, 0, 0);
    }
    __builtin_amdgcn_s_setprio(0);
  }

  // epilogue: out = oacc / lacc  (identical lane layout, no cross-lane ops)
#pragma unroll
  for (int r = 0; r < 16; ++r) {
    int q = (r & 3) + 8 * (r >> 2) + 4 * hi;
    float li = frcp(lacc[r]);
    size_t orow = (rowbase + q0 + q) * (size_t)768 + h * 64;
    z[orow + l31]      = f2bf(oacc0[r] * li);
    z[orow + 32 + l31] = f2bf(oacc1[r] * li);
  }
}

extern "C" void kernel_launch(void* const* d_in, const int* in_sizes, int n_in,
                              void* d_out, int out_size, void* d_ws, size_t ws_size,
                              hipStream_t stream) {
  (void)in_sizes; (void)n_in; (void)out_size; (void)ws_size;
  const float* x      = (const float*)d_in[0];
  const float* w_qkv  = (const float*)d_in[1];
  const float* b_qkv  = (const float*)d_in[2];
  const float* w_proj = (const float*)d_in[3];
  const float* b_proj = (const float*)d_in[4];
  float* out = (float*)d_out;

  const int BS = 16 * 1024;  // B*S rows
  const int D = 768, N3 = 2304;
  const float QSC = 0.180336880f;    // 0.125 * log2(e)

  u16* xb  = (u16*)d_ws;                     // [BS, D]   (reused as vt after gemm1)
  u16* wqb = xb  + (size_t)BS * D;           // [N3, D]
  u16* wpb = wqb + (size_t)N3 * D;           // [D, D]
  u16* qkv = wpb + (size_t)D * D;            // [BS, N3]
  u16* zb  = qkv + (size_t)BS * N3;          // [BS, D]
  u16* vtb = xb;                             // aliases xb

  cvt3_kernel<<<2048, 256, 0, stream>>>(x, xb, BS * D / 4,
                                        w_qkv, wqb, N3 * D / 4,
                                        w_proj, wpb, D * D / 4);

  gemm_bt128<false><<<(BS / 128) * (N3 / 128), 256, 0, stream>>>(
      xb, wqb, b_qkv, qkv, BS, N3, D, 768, QSC);
  vtrans_kernel<<<192 * 16, 256, 0, stream>>>(qkv, vtb);
  attn8_kernel<<<192 * 4, 512, 0, stream>>>(qkv, vtb, zb);
  gemm_bt128<true><<<(BS / 128) * (D / 128), 256, 0, stream>>>(
      zb, wpb, b_proj, out, BS, D, D, 0, 1.0f);
}